// Round 10
// baseline (183.051 us; speedup 1.0000x reference)
//
#include <hip/hip_runtime.h>
#include <hip/hip_bf16.h>
#include <math.h>

// Problem dims (fixed)
#define B 4
#define S 1024
#define E 512
#define H 64
#define DK 8
#define FFN 2048
#define BS (B*S)          // 4096 tokens

// kv pre-scale: CSCALE^2 = (1/sqrt(8)) * log2(e) so exp(score/sqrt(8)) = 2^(scaled score)
#define CSCALE 0.7141879f

#if __has_builtin(__builtin_amdgcn_exp2f)
#define EXP2F(x) __builtin_amdgcn_exp2f(x)
#else
#define EXP2F(x) exp2f(x)
#endif

typedef __attribute__((ext_vector_type(8))) short short8;   // 8 bf16 (4 VGPRs)
typedef __attribute__((ext_vector_type(4))) short short4v;  // 4 bf16 (b64)
typedef __attribute__((ext_vector_type(4))) float float4a;  // MFMA C/D frag

union U8 { short8 v; unsigned u[4]; };
union F4 { float4a v; float f[4]; };

__device__ __forceinline__ unsigned short f2bf(float f) {
    unsigned u = __builtin_bit_cast(unsigned, f);
    u = (u + 0x7fffu + ((u >> 16) & 1u)) >> 16;
    return (unsigned short)u;
}
__device__ __forceinline__ float bf2f(unsigned short h) {
    return __builtin_bit_cast(float, (unsigned)h << 16);
}
// one-op pack: (trunc_bf16(a) << 16) | trunc_bf16(b)
__device__ __forceinline__ unsigned packbf(float a, float b) {
    return __builtin_amdgcn_perm(__builtin_bit_cast(unsigned, a),
                                 __builtin_bit_cast(unsigned, b), 0x07060302u);
}
__device__ __forceinline__ unsigned packbf_rn(float a, float b) {
    return ((unsigned)f2bf(a) << 16) | f2bf(b);
}
// key permutation within 32-blocks (attention PV): frag pos g*8+4h+r <-> key 16h+4g+r
// Preserves low 2 bits -> 4 consecutive rows (r%4==0) map to 4 consecutive slots.
__device__ __forceinline__ int pidx(int k) {
    return (k & ~31) | (((k >> 2) & 3) << 3) | (((k >> 4) & 1) << 2) | (k & 3);
}

// ---------------------------------------------------------------------------
// K1: [blocks 0..511] MFMA attention (512 thr, half-head each).
//     [blocks 512..847] weight conversion to frag-major bf16 (R7/R8 layout).
// Staging vectorized: thread per 4 rows -> 4 ds_write_b128 (kv) + 9 b64 (vtp),
// 4x fewer DS ops than the R8 per-row u16 scatter.
// ---------------------------------------------------------------------------
__global__ __launch_bounds__(512) void attn_conv_kernel(const float* __restrict__ x,
                                                        const float* __restrict__ phi,
                                                        const float* __restrict__ Wc,
                                                        const float* __restrict__ W2,
                                                        const float* __restrict__ W1,
                                                        const float* __restrict__ b1,
                                                        unsigned short* __restrict__ Afrag,
                                                        unsigned short* __restrict__ W2f,
                                                        unsigned short* __restrict__ Wcf,
                                                        unsigned short* __restrict__ W1f) {
    __shared__ unsigned short kv[(S + 16) * DK];   // 16.25 KB, rows S..S+15 zero
    __shared__ unsigned short vtp[9][S + 8];       // 18.6 KB [dim0..7 + ones][perm key]
    int bid = blockIdx.x;
    int tid = threadIdx.x;

    if (bid >= 512) {                               // ---- convert part ----
        int idx = (bid - 512) * 512 + tid;
        if (idx < 131072) {                         // W2f (pi-permuted k)
            int lane = idx & 63, c = idx >> 6;
            int ntile = c >> 6, kb32 = c & 63;
            int g = lane >> 4, col = lane & 15;
            int n = ntile * 16 + col, kb = kb32 * 32;
            short8 o;
            #pragma unroll
            for (int j = 0; j < 8; j++) {
                int k = kb + 16 * (j >> 2) + 4 * g + (j & 3);
                o[j] = (short)f2bf(W2[(size_t)k * 512 + n]);
            }
            *(short8*)&W2f[(size_t)idx * 8] = o;
        } else if (idx < 163840) {                  // Wcf (direct frag order)
            int i2 = idx - 131072;
            int lane = i2 & 63, c = i2 >> 6;
            int ntile = c >> 4, kb32 = c & 15;
            int g = lane >> 4, col = lane & 15;
            int n = ntile * 16 + col, kb = kb32 * 32;
            short8 o;
            #pragma unroll
            for (int j = 0; j < 8; j++)
                o[j] = (short)f2bf(Wc[(size_t)(kb + g * 8 + j) * 512 + n]);
            *(short8*)&Wcf[(size_t)i2 * 8] = o;
        } else {                                    // W1f (b1 folded at slot 8)
            int i3 = idx - 163840;
            int lane = i3 & 63, c = i3 >> 6;
            int g = lane >> 4, col = lane & 15;
            int f = (c >> 1) * 32 + (c & 1) * 16 + col;
            short8 o = {0,0,0,0,0,0,0,0};
            if (g == 0) {
                #pragma unroll
                for (int j = 0; j < 8; j++) o[j] = (short)f2bf(W1[j * FFN + f]);
            } else if (g == 1) {
                o[0] = (short)f2bf(b1[f]);
            }
            *(short8*)&W1f[(size_t)i3 * 8] = o;
        }
        return;
    }

    // ---- attention part ----
    int head = bid >> 1, qhalf = bid & 1;
    int b = head >> 6, hh = head & 63;

    float ph[DK];
    #pragma unroll
    for (int d = 0; d < DK; d++) ph[d] = phi[d];

    const short8 z8 = {0,0,0,0,0,0,0,0};
    if (tid < 256) {                        // 4 consecutive rows per thread
        int r4 = tid * 4;
        unsigned short vb[8][4];
        #pragma unroll
        for (int j = 0; j < 4; j++) {
            const float* xp = x + ((size_t)(b * S + r4 + j)) * E + hh * DK;
            float4 u = *(const float4*)xp;
            float4 v = *(const float4*)(xp + 4);
            float c[8] = {__cosf(u.x+ph[0]), __cosf(u.y+ph[1]), __cosf(u.z+ph[2]), __cosf(u.w+ph[3]),
                          __cosf(v.x+ph[4]), __cosf(v.y+ph[5]), __cosf(v.z+ph[6]), __cosf(v.w+ph[7])};
            U8 kr;
            kr.u[0] = packbf_rn(c[1] * CSCALE, c[0] * CSCALE);
            kr.u[1] = packbf_rn(c[3] * CSCALE, c[2] * CSCALE);
            kr.u[2] = packbf_rn(c[5] * CSCALE, c[4] * CSCALE);
            kr.u[3] = packbf_rn(c[7] * CSCALE, c[6] * CSCALE);
            *(short8*)&kv[(r4 + j) * DK] = kr.v;    // ds_write_b128
            #pragma unroll
            for (int d = 0; d < 8; d++) vb[d][j] = f2bf(c[d]);
        }
        int pr = pidx(r4);                  // low 2 bits 0 -> 4 consecutive slots
        #pragma unroll
        for (int d = 0; d < 8; d++) {
            short4v o = {(short)vb[d][0], (short)vb[d][1], (short)vb[d][2], (short)vb[d][3]};
            *(short4v*)&vtp[d][pr] = o;             // ds_write_b64
        }
        short4v ones = {(short)0x3F80, (short)0x3F80, (short)0x3F80, (short)0x3F80};
        *(short4v*)&vtp[8][pr] = ones;
    }
    if (tid < 16) *(short8*)&kv[(S + tid) * DK] = z8;   // zero rows
    __syncthreads();

    int w = tid >> 6, lane = tid & 63, col = lane & 15, g = lane >> 4;
    bool g0 = (g == 0);
    int q0 = qhalf * 512 + w * 64;
    const float4a zc = {0.f,0.f,0.f,0.f};

    short8 aq[4];                            // Q B-frags, 4 q-tiles of 16
    #pragma unroll
    for (int t = 0; t < 4; t++)
        aq[t] = g0 ? *(const short8*)&kv[(q0 + t*16 + col) * DK] : z8;

    float4a acc[4];
    #pragma unroll
    for (int t = 0; t < 4; t++) acc[t] = zc;

    int vrow = col < 8 ? col : 8;            // clamp: dims 9..15 get denom dups
    const unsigned short* vbase = &vtp[vrow][0];

    int off0 = g0 ? col * DK : S * DK;       // zero-row pointer trick
    int off1 = g0 ? (16 + col) * DK : S * DK;
    int stepo = g0 ? 32 * DK : 0;

    for (int kb = 0; kb < S; kb += 32) {
        short8 bk0 = *(const short8*)&kv[off0];
        short8 bk1 = *(const short8*)&kv[off1];
        off0 += stepo; off1 += stepo;
        short8 vf = *(const short8*)(vbase + kb + g * 8);
        #pragma unroll
        for (int t = 0; t < 4; t++) {
            float4a s0 = __builtin_amdgcn_mfma_f32_16x16x32_bf16(bk0, aq[t], zc, 0,0,0);
            float4a s1 = __builtin_amdgcn_mfma_f32_16x16x32_bf16(bk1, aq[t], zc, 0,0,0);
            F4 S0, S1; S0.v = s0; S1.v = s1;
            float e00 = EXP2F(S0.f[0]);
            float e01 = EXP2F(S0.f[1]);
            float e02 = EXP2F(S0.f[2]);
            float e03 = EXP2F(S0.f[3]);
            float e10 = EXP2F(S1.f[0]);
            float e11 = EXP2F(S1.f[1]);
            float e12 = EXP2F(S1.f[2]);
            float e13 = EXP2F(S1.f[3]);
            U8 pf;                           // lane-local P^T B-frag (pi-ordered keys)
            pf.u[0] = packbf(e01, e00);
            pf.u[1] = packbf(e03, e02);
            pf.u[2] = packbf(e11, e10);
            pf.u[3] = packbf(e13, e12);
            acc[t] = __builtin_amdgcn_mfma_f32_16x16x32_bf16(vf, pf.v, acc[t], 0,0,0);
        }
    }
    // acc[t]: O'[dim=4g+r][q=col]; denom = dim 8 = lane 32+col, reg 0
    int lp8 = ((hh & 3) * 16 + col) * 8;     // lane' * 8 (u16 units)
    #pragma unroll
    for (int t = 0; t < 4; t++) {
        F4 a; a.v = acc[t];
        float denom = __shfl(a.f[0], 32 + col);
        float inv = __builtin_amdgcn_rcpf(denom);
        if (g < 2) {
            int chunk = (hh >> 2) * 256 + ((b << 6) | (qhalf << 5) | (w << 2) | t);
            uint2 o;
            o.x = packbf_rn(a.f[1] * inv, a.f[0] * inv);
            o.y = packbf_rn(a.f[3] * inv, a.f[2] * inv);
            *(uint2*)&Afrag[(size_t)chunk * 512 + lp8 + g * 4] = o;
        }
    }
}

// ---------------------------------------------------------------------------
// K2: combine-heads GEMM + fused LN1 + qout (unchanged from R8, validated).
// Block = 16 tokens x full 512 n (8 waves x 4 ntiles).
// ---------------------------------------------------------------------------
__global__ __launch_bounds__(512) void combine_ln1(const unsigned short* __restrict__ Afrag,
                                                   const unsigned short* __restrict__ Wcf,
                                                   const float* __restrict__ bc,
                                                   const float* __restrict__ x,
                                                   const float* __restrict__ g1,
                                                   const float* __restrict__ be1,
                                                   float* __restrict__ x1out,
                                                   unsigned short* __restrict__ qoutbf,
                                                   const float* __restrict__ theta) {
    __shared__ unsigned short As[16 * 64 * 8];      // 16 KB
    __shared__ float xout[16][516];                 // 33 KB
    int tt = blockIdx.x;
    int tid = threadIdx.x;

    for (int i = tid; i < 1024; i += 512)
        *(short8*)&As[i * 8] =
            *(const short8*)&Afrag[((size_t)((i >> 6) * 256 + tt) * 64 + (i & 63)) * 8];
    __syncthreads();

    int w = tid >> 6, lane = tid & 63, col = lane & 15, g = lane >> 4;
    const float4a zc = {0.f,0.f,0.f,0.f};
    float4a acc[4];
    #pragma unroll
    for (int nt = 0; nt < 4; nt++) acc[nt] = zc;

    for (int kb32 = 0; kb32 < 16; kb32++) {
        short8 af = *(const short8*)&As[(kb32 * 64 + lane) * 8];
        #pragma unroll
        for (int nt = 0; nt < 4; nt++) {
            short8 bf = *(const short8*)&Wcf[((size_t)((w * 4 + nt) * 16 + kb32) * 64 + lane) * 8];
            acc[nt] = __builtin_amdgcn_mfma_f32_16x16x32_bf16(af, bf, acc[nt], 0, 0, 0);
        }
    }
    #pragma unroll
    for (int nt = 0; nt < 4; nt++) {
        int n = w * 64 + nt * 16 + col;
        float bb = bc[n];
        #pragma unroll
        for (int r = 0; r < 4; r++)
            xout[g * 4 + r][n] = acc[nt][r] + bb;
    }
    __syncthreads();

    int hl = lane >> 5, l = lane & 31;
    int token = w * 2 + hl;
    int e0 = l * 16;
    size_t grow = ((size_t)tt * 16 + token) * 512;
    float v[16];
    float s = 0.f, sq = 0.f;
    #pragma unroll
    for (int u = 0; u < 4; u++) {
        float4 xv = *(const float4*)&x[grow + e0 + u * 4];
        float4 pv = *(const float4*)&xout[token][e0 + u * 4];
        float a0 = xv.x + pv.x, a1 = xv.y + pv.y, a2 = xv.z + pv.z, a3 = xv.w + pv.w;
        v[u*4] = a0; v[u*4+1] = a1; v[u*4+2] = a2; v[u*4+3] = a3;
        s += a0 + a1 + a2 + a3;
        sq += a0*a0 + a1*a1 + a2*a2 + a3*a3;
    }
    #pragma unroll
    for (int off = 1; off <= 16; off <<= 1) {
        s  += __shfl_xor(s, off);
        sq += __shfl_xor(sq, off);
    }
    float mu = s * (1.f / 512.f);
    float var = sq * (1.f / 512.f) - mu * mu;
    float rstd = rsqrtf(var + 1e-5f);
    float y[16];
    #pragma unroll
    for (int u = 0; u < 4; u++) {
        float4 gv = *(const float4*)&g1[e0 + u * 4];
        float4 bv = *(const float4*)&be1[e0 + u * 4];
        y[u*4]   = (v[u*4]   - mu) * rstd * gv.x + bv.x;
        y[u*4+1] = (v[u*4+1] - mu) * rstd * gv.y + bv.y;
        y[u*4+2] = (v[u*4+2] - mu) * rstd * gv.z + bv.z;
        y[u*4+3] = (v[u*4+3] - mu) * rstd * gv.w + bv.w;
        float4 o = make_float4(y[u*4], y[u*4+1], y[u*4+2], y[u*4+3]);
        *(float4*)&x1out[grow + e0 + u * 4] = o;
    }
    if (l == 0) {
        U8 q;
        q.u[0] = packbf_rn(__cosf(y[1]) * __cosf(theta[1]), __cosf(y[0]) * __cosf(theta[0]));
        q.u[1] = packbf_rn(__cosf(y[3]) * __cosf(theta[3]), __cosf(y[2]) * __cosf(theta[2]));
        q.u[2] = packbf_rn(__cosf(y[5]) * __cosf(theta[5]), __cosf(y[4]) * __cosf(theta[4]));
        q.u[3] = packbf_rn(__cosf(y[7]) * __cosf(theta[7]), __cosf(y[6]) * __cosf(theta[6]));
        *(short8*)&qoutbf[((size_t)tt * 16 + token) * 8] = q.v;
    }
}

// ---------------------------------------------------------------------------
// K3: FFN + fused LN2. Block = 16 tokens x full 512 n (8 waves x 4 ntiles,
// 256 blocks). W1 frags from global (wave-uniform address -> L1 broadcast);
// b1 folded at k-slot 8. C rows land in LDS -> in-block LN2 -> final out.
// ---------------------------------------------------------------------------
__global__ __launch_bounds__(512) void ffn_ln2(const unsigned short* __restrict__ qbf,
                                               const unsigned short* __restrict__ W1f,
                                               const unsigned short* __restrict__ W2f,
                                               const float* __restrict__ b2,
                                               const float* __restrict__ g2,
                                               const float* __restrict__ be2,
                                               float* out) {    // x1 in, final out
    __shared__ float xout[16][516];                 // 33 KB
    int tt = blockIdx.x;
    int tid = threadIdx.x;
    int w = tid >> 6, lane = tid & 63, col = lane & 15, g = lane >> 4;
    const short8 z8 = {0,0,0,0,0,0,0,0};
    const short8 one8 = {(short)0x3F80,0,0,0,0,0,0,0};
    const float4a zc = {0.f,0.f,0.f,0.f};

    short8 qf = (g == 0) ? *(const short8*)&qbf[(size_t)(tt * 16 + col) * 8]
                         : (g == 1 ? one8 : z8);

    float4a acc[4];
    #pragma unroll
    for (int nt = 0; nt < 4; nt++) acc[nt] = zc;

    const unsigned short* w1p = W1f + lane * 8;
    for (int kb32 = 0; kb32 < 64; kb32++) {
        short8 w1f0 = *(const short8*)(w1p + (size_t)(kb32 * 2) * 512);
        short8 w1f1 = *(const short8*)(w1p + (size_t)(kb32 * 2 + 1) * 512);
        float4a h0 = __builtin_amdgcn_mfma_f32_16x16x32_bf16(w1f0, qf, zc, 0,0,0);
        float4a h1 = __builtin_amdgcn_mfma_f32_16x16x32_bf16(w1f1, qf, zc, 0,0,0);
        F4 H0, H1; H0.v = h0; H1.v = h1;
        float e00 = fmaxf(H0.f[0], 0.f);
        float e01 = fmaxf(H0.f[1], 0.f);
        float e02 = fmaxf(H0.f[2], 0.f);
        float e03 = fmaxf(H0.f[3], 0.f);
        float e10 = fmaxf(H1.f[0], 0.f);
        float e11 = fmaxf(H1.f[1], 0.f);
        float e12 = fmaxf(H1.f[2], 0.f);
        float e13 = fmaxf(H1.f[3], 0.f);
        U8 pf;                               // H^T B-frag, pi-ordered f
        pf.u[0] = packbf(e01, e00);
        pf.u[1] = packbf(e03, e02);
        pf.u[2] = packbf(e11, e10);
        pf.u[3] = packbf(e13, e12);
        #pragma unroll
        for (int nt = 0; nt < 4; nt++) {
            short8 af = *(const short8*)&W2f[((size_t)((w * 4 + nt) * 64 + kb32) * 64 + lane) * 8];
            acc[nt] = __builtin_amdgcn_mfma_f32_16x16x32_bf16(af, pf.v, acc[nt], 0,0,0);
        }
    }
    // acc[nt]: OUT^T[n_loc=4g+r][tok=col]; n = (w*4+nt)*16 + 4g + r (contig in r)
    #pragma unroll
    for (int nt = 0; nt < 4; nt++) {
        int n = (w * 4 + nt) * 16 + 4 * g;
        float4 bb = *(const float4*)&b2[n];
        F4 a; a.v = acc[nt];
        *(float4*)&xout[col][n] = make_float4(a.f[0] + bb.x, a.f[1] + bb.y,
                                              a.f[2] + bb.z, a.f[3] + bb.w);
    }
    __syncthreads();

    // LN2: wave w handles tokens 2w, 2w+1 (32 lanes each, 16 elems/lane)
    int hl = lane >> 5, l = lane & 31;
    int token = w * 2 + hl;
    int e0 = l * 16;
    size_t grow = ((size_t)tt * 16 + token) * 512;
    float v[16];
    float s = 0.f, sq = 0.f;
    #pragma unroll
    for (int u = 0; u < 4; u++) {
        float4 xv = *(const float4*)&out[grow + e0 + u * 4];     // x1
        float4 pv = *(const float4*)&xout[token][e0 + u * 4];    // ffn_out
        float a0 = xv.x + pv.x, a1 = xv.y + pv.y, a2 = xv.z + pv.z, a3 = xv.w + pv.w;
        v[u*4] = a0; v[u*4+1] = a1; v[u*4+2] = a2; v[u*4+3] = a3;
        s += a0 + a1 + a2 + a3;
        sq += a0*a0 + a1*a1 + a2*a2 + a3*a3;
    }
    #pragma unroll
    for (int off = 1; off <= 16; off <<= 1) {
        s  += __shfl_xor(s, off);
        sq += __shfl_xor(sq, off);
    }
    float mu = s * (1.f / 512.f);
    float var = sq * (1.f / 512.f) - mu * mu;
    float rstd = rsqrtf(var + 1e-5f);
    #pragma unroll
    for (int u = 0; u < 4; u++) {
        float4 gv = *(const float4*)&g2[e0 + u * 4];
        float4 bv = *(const float4*)&be2[e0 + u * 4];
        float4 o = make_float4((v[u*4]   - mu) * rstd * gv.x + bv.x,
                               (v[u*4+1] - mu) * rstd * gv.y + bv.y,
                               (v[u*4+2] - mu) * rstd * gv.z + bv.z,
                               (v[u*4+3] - mu) * rstd * gv.w + bv.w);
        *(float4*)&out[grow + e0 + u * 4] = o;
    }
}

// ---------------------------------------------------------------------------
// launch — 3 kernels. ws: Afrag 4MB | W2f 2MB | Wcf 0.5MB | W1f 128KB
// | qoutbf 64KB = 6.7 MB (under proven 8.13 MB). d_out: x1 fp32 then final.
// ---------------------------------------------------------------------------
extern "C" void kernel_launch(void* const* d_in, const int* in_sizes, int n_in,
                              void* d_out, int out_size, void* d_ws, size_t ws_size,
                              hipStream_t stream) {
    const float* x     = (const float*)d_in[0];
    const float* phi   = (const float*)d_in[1];
    const float* Wc    = (const float*)d_in[2];
    const float* bc    = (const float*)d_in[3];
    const float* theta = (const float*)d_in[4];
    const float* W1    = (const float*)d_in[5];
    const float* b1    = (const float*)d_in[6];
    const float* W2    = (const float*)d_in[7];
    const float* b2    = (const float*)d_in[8];
    const float* g1    = (const float*)d_in[9];
    const float* be1   = (const float*)d_in[10];
    const float* g2    = (const float*)d_in[11];
    const float* be2   = (const float*)d_in[12];
    float* out = (float*)d_out;

    float* ws = (float*)d_ws;
    unsigned short* Afrag  = (unsigned short*)ws;                       // 4 MB
    unsigned short* W2f    = (unsigned short*)(ws + 1048576);           // 2 MB
    unsigned short* Wcf    = (unsigned short*)(ws + 1572864);           // 512 KB
    unsigned short* W1f    = (unsigned short*)(ws + 1703936);           // 128 KB
    unsigned short* qoutbf = (unsigned short*)(ws + 1736704);           // 64 KB

    attn_conv_kernel<<<848, 512, 0, stream>>>(x, phi, Wc, W2, W1, b1,
                                              Afrag, W2f, Wcf, W1f);
    combine_ln1<<<256, 512, 0, stream>>>(Afrag, Wcf, bc, x, g1, be1,
                                         out, qoutbf, theta);
    ffn_ln2<<<256, 512, 0, stream>>>(qoutbf, W1f, W2f, b2, g2, be2, out);
}

// Round 11
// 164.988 us; speedup vs baseline: 1.1095x; 1.1095x over previous
//
#include <hip/hip_runtime.h>
#include <hip/hip_bf16.h>
#include <math.h>

// Problem dims (fixed)
#define B 4
#define S 1024
#define E 512
#define H 64
#define DK 8
#define FFN 2048
#define BS (B*S)          // 4096 tokens

// kv pre-scale: CSCALE^2 = (1/sqrt(8)) * log2(e) so exp(score/sqrt(8)) = 2^(scaled score)
#define CSCALE 0.7141879f

#if __has_builtin(__builtin_amdgcn_exp2f)
#define EXP2F(x) __builtin_amdgcn_exp2f(x)
#else
#define EXP2F(x) exp2f(x)
#endif

typedef __attribute__((ext_vector_type(8))) short short8;   // 8 bf16 (4 VGPRs)
typedef __attribute__((ext_vector_type(4))) short short4v;  // 4 bf16 (b64)
typedef __attribute__((ext_vector_type(4))) float float4a;  // MFMA C/D frag

union U8 { short8 v; unsigned u[4]; };
union F4 { float4a v; float f[4]; };

__device__ __forceinline__ unsigned short f2bf(float f) {
    unsigned u = __builtin_bit_cast(unsigned, f);
    u = (u + 0x7fffu + ((u >> 16) & 1u)) >> 16;
    return (unsigned short)u;
}
__device__ __forceinline__ float bf2f(unsigned short h) {
    return __builtin_bit_cast(float, (unsigned)h << 16);
}
// one-op pack: (trunc_bf16(a) << 16) | trunc_bf16(b)
__device__ __forceinline__ unsigned packbf(float a, float b) {
    return __builtin_amdgcn_perm(__builtin_bit_cast(unsigned, a),
                                 __builtin_bit_cast(unsigned, b), 0x07060302u);
}
__device__ __forceinline__ unsigned packbf_rn(float a, float b) {
    return ((unsigned)f2bf(a) << 16) | f2bf(b);
}
// key permutation within 32-blocks (attention PV): frag pos g*8+4h+r <-> key 16h+4g+r
// Preserves low 2 bits -> 4 consecutive rows (r%4==0) map to 4 consecutive slots.
__device__ __forceinline__ int pidx(int k) {
    return (k & ~31) | (((k >> 2) & 3) << 3) | (((k >> 4) & 1) << 2) | (k & 3);
}

// ---------------------------------------------------------------------------
// K1: [blocks 0..511] MFMA attention (512 thr, half-head each).
//     [blocks 512..847] weight conversion to frag-major bf16.
// Staging vectorized (R10): thread per 4 rows -> 4 ds_write_b128 + 9 b64.
// ---------------------------------------------------------------------------
__global__ __launch_bounds__(512) void attn_conv_kernel(const float* __restrict__ x,
                                                        const float* __restrict__ phi,
                                                        const float* __restrict__ Wc,
                                                        const float* __restrict__ W2,
                                                        const float* __restrict__ W1,
                                                        const float* __restrict__ b1,
                                                        unsigned short* __restrict__ Afrag,
                                                        unsigned short* __restrict__ W2f,
                                                        unsigned short* __restrict__ Wcf,
                                                        unsigned short* __restrict__ W1f) {
    __shared__ unsigned short kv[(S + 16) * DK];   // 16.25 KB, rows S..S+15 zero
    __shared__ unsigned short vtp[9][S + 8];       // 18.6 KB [dim0..7 + ones][perm key]
    int bid = blockIdx.x;
    int tid = threadIdx.x;

    if (bid >= 512) {                               // ---- convert part ----
        int idx = (bid - 512) * 512 + tid;
        if (idx < 131072) {                         // W2f (pi-permuted k)
            int lane = idx & 63, c = idx >> 6;
            int ntile = c >> 6, kb32 = c & 63;
            int g = lane >> 4, col = lane & 15;
            int n = ntile * 16 + col, kb = kb32 * 32;
            short8 o;
            #pragma unroll
            for (int j = 0; j < 8; j++) {
                int k = kb + 16 * (j >> 2) + 4 * g + (j & 3);
                o[j] = (short)f2bf(W2[(size_t)k * 512 + n]);
            }
            *(short8*)&W2f[(size_t)idx * 8] = o;
        } else if (idx < 163840) {                  // Wcf (direct frag order)
            int i2 = idx - 131072;
            int lane = i2 & 63, c = i2 >> 6;
            int ntile = c >> 4, kb32 = c & 15;
            int g = lane >> 4, col = lane & 15;
            int n = ntile * 16 + col, kb = kb32 * 32;
            short8 o;
            #pragma unroll
            for (int j = 0; j < 8; j++)
                o[j] = (short)f2bf(Wc[(size_t)(kb + g * 8 + j) * 512 + n]);
            *(short8*)&Wcf[(size_t)i2 * 8] = o;
        } else {                                    // W1f (b1 folded at slot 8)
            int i3 = idx - 163840;
            int lane = i3 & 63, c = i3 >> 6;
            int g = lane >> 4, col = lane & 15;
            int f = (c >> 1) * 32 + (c & 1) * 16 + col;
            short8 o = {0,0,0,0,0,0,0,0};
            if (g == 0) {
                #pragma unroll
                for (int j = 0; j < 8; j++) o[j] = (short)f2bf(W1[j * FFN + f]);
            } else if (g == 1) {
                o[0] = (short)f2bf(b1[f]);
            }
            *(short8*)&W1f[(size_t)i3 * 8] = o;
        }
        return;
    }

    // ---- attention part ----
    int head = bid >> 1, qhalf = bid & 1;
    int b = head >> 6, hh = head & 63;

    float ph[DK];
    #pragma unroll
    for (int d = 0; d < DK; d++) ph[d] = phi[d];

    const short8 z8 = {0,0,0,0,0,0,0,0};
    if (tid < 256) {                        // 4 consecutive rows per thread
        int r4 = tid * 4;
        unsigned short vb[8][4];
        #pragma unroll
        for (int j = 0; j < 4; j++) {
            const float* xp = x + ((size_t)(b * S + r4 + j)) * E + hh * DK;
            float4 u = *(const float4*)xp;
            float4 v = *(const float4*)(xp + 4);
            float c[8] = {__cosf(u.x+ph[0]), __cosf(u.y+ph[1]), __cosf(u.z+ph[2]), __cosf(u.w+ph[3]),
                          __cosf(v.x+ph[4]), __cosf(v.y+ph[5]), __cosf(v.z+ph[6]), __cosf(v.w+ph[7])};
            U8 kr;
            kr.u[0] = packbf_rn(c[1] * CSCALE, c[0] * CSCALE);
            kr.u[1] = packbf_rn(c[3] * CSCALE, c[2] * CSCALE);
            kr.u[2] = packbf_rn(c[5] * CSCALE, c[4] * CSCALE);
            kr.u[3] = packbf_rn(c[7] * CSCALE, c[6] * CSCALE);
            *(short8*)&kv[(r4 + j) * DK] = kr.v;    // ds_write_b128
            #pragma unroll
            for (int d = 0; d < 8; d++) vb[d][j] = f2bf(c[d]);
        }
        int pr = pidx(r4);                  // low 2 bits 0 -> 4 consecutive slots
        #pragma unroll
        for (int d = 0; d < 8; d++) {
            short4v o = {(short)vb[d][0], (short)vb[d][1], (short)vb[d][2], (short)vb[d][3]};
            *(short4v*)&vtp[d][pr] = o;             // ds_write_b64
        }
        short4v ones = {(short)0x3F80, (short)0x3F80, (short)0x3F80, (short)0x3F80};
        *(short4v*)&vtp[8][pr] = ones;
    }
    if (tid < 16) *(short8*)&kv[(S + tid) * DK] = z8;   // zero rows
    __syncthreads();

    int w = tid >> 6, lane = tid & 63, col = lane & 15, g = lane >> 4;
    bool g0 = (g == 0);
    int q0 = qhalf * 512 + w * 64;
    const float4a zc = {0.f,0.f,0.f,0.f};

    short8 aq[4];                            // Q B-frags, 4 q-tiles of 16
    #pragma unroll
    for (int t = 0; t < 4; t++)
        aq[t] = g0 ? *(const short8*)&kv[(q0 + t*16 + col) * DK] : z8;

    float4a acc[4];
    #pragma unroll
    for (int t = 0; t < 4; t++) acc[t] = zc;

    int vrow = col < 8 ? col : 8;            // clamp: dims 9..15 get denom dups
    const unsigned short* vbase = &vtp[vrow][0];

    int off0 = g0 ? col * DK : S * DK;       // zero-row pointer trick
    int off1 = g0 ? (16 + col) * DK : S * DK;
    int stepo = g0 ? 32 * DK : 0;

    for (int kb = 0; kb < S; kb += 32) {
        short8 bk0 = *(const short8*)&kv[off0];
        short8 bk1 = *(const short8*)&kv[off1];
        off0 += stepo; off1 += stepo;
        short8 vf = *(const short8*)(vbase + kb + g * 8);
        #pragma unroll
        for (int t = 0; t < 4; t++) {
            float4a s0 = __builtin_amdgcn_mfma_f32_16x16x32_bf16(bk0, aq[t], zc, 0,0,0);
            float4a s1 = __builtin_amdgcn_mfma_f32_16x16x32_bf16(bk1, aq[t], zc, 0,0,0);
            F4 S0, S1; S0.v = s0; S1.v = s1;
            float e00 = EXP2F(S0.f[0]);
            float e01 = EXP2F(S0.f[1]);
            float e02 = EXP2F(S0.f[2]);
            float e03 = EXP2F(S0.f[3]);
            float e10 = EXP2F(S1.f[0]);
            float e11 = EXP2F(S1.f[1]);
            float e12 = EXP2F(S1.f[2]);
            float e13 = EXP2F(S1.f[3]);
            U8 pf;                           // lane-local P^T B-frag (pi-ordered keys)
            pf.u[0] = packbf(e01, e00);
            pf.u[1] = packbf(e03, e02);
            pf.u[2] = packbf(e11, e10);
            pf.u[3] = packbf(e13, e12);
            acc[t] = __builtin_amdgcn_mfma_f32_16x16x32_bf16(vf, pf.v, acc[t], 0,0,0);
        }
    }
    // acc[t]: O'[dim=4g+r][q=col]; denom = dim 8 = lane 32+col, reg 0
    int lp8 = ((hh & 3) * 16 + col) * 8;     // lane' * 8 (u16 units)
    #pragma unroll
    for (int t = 0; t < 4; t++) {
        F4 a; a.v = acc[t];
        float denom = __shfl(a.f[0], 32 + col);
        float inv = __builtin_amdgcn_rcpf(denom);
        if (g < 2) {
            int chunk = (hh >> 2) * 256 + ((b << 6) | (qhalf << 5) | (w << 2) | t);
            uint2 o;
            o.x = packbf_rn(a.f[1] * inv, a.f[0] * inv);
            o.y = packbf_rn(a.f[3] * inv, a.f[2] * inv);
            *(uint2*)&Afrag[(size_t)chunk * 512 + lp8 + g * 4] = o;
        }
    }
}

// ---------------------------------------------------------------------------
// K2: combine-heads GEMM + fused LN1 + qout (validated R8/R10).
// Block = 16 tokens x full 512 n (8 waves x 4 ntiles).
// ---------------------------------------------------------------------------
__global__ __launch_bounds__(512) void combine_ln1(const unsigned short* __restrict__ Afrag,
                                                   const unsigned short* __restrict__ Wcf,
                                                   const float* __restrict__ bc,
                                                   const float* __restrict__ x,
                                                   const float* __restrict__ g1,
                                                   const float* __restrict__ be1,
                                                   float* __restrict__ x1out,
                                                   unsigned short* __restrict__ qoutbf,
                                                   const float* __restrict__ theta) {
    __shared__ unsigned short As[16 * 64 * 8];      // 16 KB
    __shared__ float xout[16][516];                 // 33 KB
    int tt = blockIdx.x;
    int tid = threadIdx.x;

    for (int i = tid; i < 1024; i += 512)
        *(short8*)&As[i * 8] =
            *(const short8*)&Afrag[((size_t)((i >> 6) * 256 + tt) * 64 + (i & 63)) * 8];
    __syncthreads();

    int w = tid >> 6, lane = tid & 63, col = lane & 15, g = lane >> 4;
    const float4a zc = {0.f,0.f,0.f,0.f};
    float4a acc[4];
    #pragma unroll
    for (int nt = 0; nt < 4; nt++) acc[nt] = zc;

    for (int kb32 = 0; kb32 < 16; kb32++) {
        short8 af = *(const short8*)&As[(kb32 * 64 + lane) * 8];
        #pragma unroll
        for (int nt = 0; nt < 4; nt++) {
            short8 bf = *(const short8*)&Wcf[((size_t)((w * 4 + nt) * 16 + kb32) * 64 + lane) * 8];
            acc[nt] = __builtin_amdgcn_mfma_f32_16x16x32_bf16(af, bf, acc[nt], 0, 0, 0);
        }
    }
    #pragma unroll
    for (int nt = 0; nt < 4; nt++) {
        int n = w * 64 + nt * 16 + col;
        float bb = bc[n];
        #pragma unroll
        for (int r = 0; r < 4; r++)
            xout[g * 4 + r][n] = acc[nt][r] + bb;
    }
    __syncthreads();

    int hl = lane >> 5, l = lane & 31;
    int token = w * 2 + hl;
    int e0 = l * 16;
    size_t grow = ((size_t)tt * 16 + token) * 512;
    float v[16];
    float s = 0.f, sq = 0.f;
    #pragma unroll
    for (int u = 0; u < 4; u++) {
        float4 xv = *(const float4*)&x[grow + e0 + u * 4];
        float4 pv = *(const float4*)&xout[token][e0 + u * 4];
        float a0 = xv.x + pv.x, a1 = xv.y + pv.y, a2 = xv.z + pv.z, a3 = xv.w + pv.w;
        v[u*4] = a0; v[u*4+1] = a1; v[u*4+2] = a2; v[u*4+3] = a3;
        s += a0 + a1 + a2 + a3;
        sq += a0*a0 + a1*a1 + a2*a2 + a3*a3;
    }
    #pragma unroll
    for (int off = 1; off <= 16; off <<= 1) {
        s  += __shfl_xor(s, off);
        sq += __shfl_xor(sq, off);
    }
    float mu = s * (1.f / 512.f);
    float var = sq * (1.f / 512.f) - mu * mu;
    float rstd = rsqrtf(var + 1e-5f);
    float y[16];
    #pragma unroll
    for (int u = 0; u < 4; u++) {
        float4 gv = *(const float4*)&g1[e0 + u * 4];
        float4 bv = *(const float4*)&be1[e0 + u * 4];
        y[u*4]   = (v[u*4]   - mu) * rstd * gv.x + bv.x;
        y[u*4+1] = (v[u*4+1] - mu) * rstd * gv.y + bv.y;
        y[u*4+2] = (v[u*4+2] - mu) * rstd * gv.z + bv.z;
        y[u*4+3] = (v[u*4+3] - mu) * rstd * gv.w + bv.w;
        float4 o = make_float4(y[u*4], y[u*4+1], y[u*4+2], y[u*4+3]);
        *(float4*)&x1out[grow + e0 + u * 4] = o;
    }
    if (l == 0) {
        U8 q;
        q.u[0] = packbf_rn(__cosf(y[1]) * __cosf(theta[1]), __cosf(y[0]) * __cosf(theta[0]));
        q.u[1] = packbf_rn(__cosf(y[3]) * __cosf(theta[3]), __cosf(y[2]) * __cosf(theta[2]));
        q.u[2] = packbf_rn(__cosf(y[5]) * __cosf(theta[5]), __cosf(y[4]) * __cosf(theta[4]));
        q.u[3] = packbf_rn(__cosf(y[7]) * __cosf(theta[7]), __cosf(y[6]) * __cosf(theta[6]));
        *(short8*)&qoutbf[((size_t)tt * 16 + token) * 8] = q.v;
    }
}

// ---------------------------------------------------------------------------
// K3: FFN (R8 version restored verbatim — n-tiled, W1+b1 staged in LDS).
// Wave = 32 tokens x 32 n; block = 256 tok x 32 n; grid (16,16).
// ---------------------------------------------------------------------------
__global__ __launch_bounds__(512) void ffn_mfma(const unsigned short* __restrict__ qbf,
                                                const unsigned short* __restrict__ W1fg,
                                                const unsigned short* __restrict__ W2f,
                                                const float* __restrict__ b2,
                                                unsigned short* __restrict__ Cbf) {
    __shared__ unsigned short w1x[FFN * 16];   // 64 KB: [f][slot], slot8 = b1[f]
    int tid = threadIdx.x;
    #pragma unroll
    for (int i = 0; i < 8; i++) {
        int d = tid + i * 512;                 // d = f*2 + gg
        int f = d >> 1, gg = d & 1;
        int kb32 = f >> 5, half = (f >> 4) & 1, fc = f & 15;
        int src = ((kb32 * 2 + half) * 64 + gg * 16 + fc);
        *(short8*)&w1x[f * 16 + gg * 8] = *(const short8*)&W1fg[(size_t)src * 8];
    }
    __syncthreads();

    int w = tid >> 6, lane = tid & 63, col = lane & 15, g = lane >> 4;
    int mw = blockIdx.x * 256 + w * 32;
    int ntile0 = blockIdx.y * 2;
    const short8 z8 = {0,0,0,0,0,0,0,0};
    const short8 one8 = {(short)0x3F80,0,0,0,0,0,0,0};
    const float4a zc = {0.f,0.f,0.f,0.f};

    short8 qf[2];                              // B[k=qslot][n=tok]; slot8 = 1.0
    #pragma unroll
    for (int t = 0; t < 2; t++)
        qf[t] = (g == 0) ? *(const short8*)&qbf[(size_t)(mw + t * 16 + col) * 8]
                         : (g == 1 ? one8 : z8);

    float4a acc[2][2];
    acc[0][0] = zc; acc[0][1] = zc; acc[1][0] = zc; acc[1][1] = zc;

    const unsigned short* w2p0 = W2f + (size_t)(ntile0 * 64) * 512 + lane * 8;
    const unsigned short* w2p1 = W2f + (size_t)((ntile0 + 1) * 64) * 512 + lane * 8;

    for (int kb32 = 0; kb32 < 64; kb32++) {
        int kb = kb32 * 32;
        short8 w1f0 = (g < 2) ? *(const short8*)&w1x[(kb + col) * 16 + g * 8] : z8;
        short8 w1f1 = (g < 2) ? *(const short8*)&w1x[(kb + 16 + col) * 16 + g * 8] : z8;
        short8 af0 = *(const short8*)(w2p0 + (size_t)kb32 * 512);
        short8 af1 = *(const short8*)(w2p1 + (size_t)kb32 * 512);
        #pragma unroll
        for (int t = 0; t < 2; t++) {
            float4a h0 = __builtin_amdgcn_mfma_f32_16x16x32_bf16(w1f0, qf[t], zc, 0,0,0);
            float4a h1 = __builtin_amdgcn_mfma_f32_16x16x32_bf16(w1f1, qf[t], zc, 0,0,0);
            F4 H0, H1; H0.v = h0; H1.v = h1;
            float e00 = fmaxf(H0.f[0], 0.f);
            float e01 = fmaxf(H0.f[1], 0.f);
            float e02 = fmaxf(H0.f[2], 0.f);
            float e03 = fmaxf(H0.f[3], 0.f);
            float e10 = fmaxf(H1.f[0], 0.f);
            float e11 = fmaxf(H1.f[1], 0.f);
            float e12 = fmaxf(H1.f[2], 0.f);
            float e13 = fmaxf(H1.f[3], 0.f);
            U8 pf;                             // H^T B-frag, pi-ordered f
            pf.u[0] = packbf(e01, e00);
            pf.u[1] = packbf(e03, e02);
            pf.u[2] = packbf(e11, e10);
            pf.u[3] = packbf(e13, e12);
            acc[t][0] = __builtin_amdgcn_mfma_f32_16x16x32_bf16(af0, pf.v, acc[t][0], 0,0,0);
            acc[t][1] = __builtin_amdgcn_mfma_f32_16x16x32_bf16(af1, pf.v, acc[t][1], 0,0,0);
        }
    }
    int n0 = ntile0 * 16;
    #pragma unroll
    for (int nt = 0; nt < 2; nt++) {
        float4 bb = *(const float4*)&b2[n0 + nt * 16 + 4 * g];
        #pragma unroll
        for (int t = 0; t < 2; t++) {
            F4 a; a.v = acc[t][nt];
            uint2 o;
            o.x = packbf_rn(a.f[1] + bb.y, a.f[0] + bb.x);
            o.y = packbf_rn(a.f[3] + bb.w, a.f[2] + bb.z);
            *(uint2*)&Cbf[(size_t)(mw + t * 16 + col) * 512 + n0 + nt * 16 + 4 * g] = o;
        }
    }
}

// ---------------------------------------------------------------------------
// K4: final LayerNorm (x1 fp32 + ffn_out bf16), in-place on d_out.
// ---------------------------------------------------------------------------
__global__ __launch_bounds__(256) void ln_kernel(const float* a,
                                                 const unsigned short* __restrict__ r,
                                                 const float* __restrict__ g,
                                                 const float* __restrict__ be,
                                                 float* out) {
    int t = blockIdx.x, tid = threadIdx.x;
    size_t base = (size_t)t * E;
    int e0 = tid * 2;
    float2 av = *(const float2*)&a[base + e0];
    unsigned rv = *(const unsigned*)&r[base + e0];
    float v0 = av.x + bf2f((unsigned short)(rv & 0xffff));
    float v1 = av.y + bf2f((unsigned short)(rv >> 16));
    float s  = v0 + v1;
    float sq = v0 * v0 + v1 * v1;
    #pragma unroll
    for (int off = 32; off > 0; off >>= 1) {
        s  += __shfl_down(s, off);
        sq += __shfl_down(sq, off);
    }
    __shared__ float ls[4], lq[4];
    int wave = tid >> 6, lane = tid & 63;
    if (lane == 0) { ls[wave] = s; lq[wave] = sq; }
    __syncthreads();
    if (tid == 0) {
        float SS = ls[0] + ls[1] + ls[2] + ls[3];
        float QQ = lq[0] + lq[1] + lq[2] + lq[3];
        float mu = SS * (1.f / E);
        float var = QQ * (1.f / E) - mu * mu;
        ls[0] = mu;
        lq[0] = rsqrtf(var + 1e-5f);
    }
    __syncthreads();
    float mu = ls[0], rstd = lq[0];
    float2 gv = *(const float2*)&g[e0];
    float2 bv = *(const float2*)&be[e0];
    float y0 = (v0 - mu) * rstd * gv.x + bv.x;
    float y1 = (v1 - mu) * rstd * gv.y + bv.y;
    *(float2*)&out[base + e0] = make_float2(y0, y1);
}

// ---------------------------------------------------------------------------
// launch — 4 kernels. ws: Afrag/ffn_out 4MB | W2f 2MB | Wcf 0.5MB | W1f 128KB
// | qoutbf 64KB = 6.7 MB (under proven 8.13 MB). d_out: x1 fp32, LN2 in-place.
// ---------------------------------------------------------------------------
extern "C" void kernel_launch(void* const* d_in, const int* in_sizes, int n_in,
                              void* d_out, int out_size, void* d_ws, size_t ws_size,
                              hipStream_t stream) {
    const float* x     = (const float*)d_in[0];
    const float* phi   = (const float*)d_in[1];
    const float* Wc    = (const float*)d_in[2];
    const float* bc    = (const float*)d_in[3];
    const float* theta = (const float*)d_in[4];
    const float* W1    = (const float*)d_in[5];
    const float* b1    = (const float*)d_in[6];
    const float* W2    = (const float*)d_in[7];
    const float* b2    = (const float*)d_in[8];
    const float* g1    = (const float*)d_in[9];
    const float* be1   = (const float*)d_in[10];
    const float* g2    = (const float*)d_in[11];
    const float* be2   = (const float*)d_in[12];
    float* out = (float*)d_out;

    float* ws = (float*)d_ws;
    unsigned short* Afrag  = (unsigned short*)ws;                       // 4 MB (also ffn_out)
    unsigned short* W2f    = (unsigned short*)(ws + 1048576);           // 2 MB
    unsigned short* Wcf    = (unsigned short*)(ws + 1572864);           // 512 KB
    unsigned short* W1f    = (unsigned short*)(ws + 1703936);           // 128 KB
    unsigned short* qoutbf = (unsigned short*)(ws + 1736704);           // 64 KB

    attn_conv_kernel<<<848, 512, 0, stream>>>(x, phi, Wc, W2, W1, b1,
                                              Afrag, W2f, Wcf, W1f);
    combine_ln1<<<256, 512, 0, stream>>>(Afrag, Wcf, bc, x, g1, be1,
                                         out, qoutbf, theta);
    ffn_mfma<<<dim3(16, 16), 512, 0, stream>>>(qoutbf, W1f, W2f, b2, Afrag);
    ln_kernel<<<BS, 256, 0, stream>>>(out, Afrag, g2, be2, out);
}

// Round 12
// 161.321 us; speedup vs baseline: 1.1347x; 1.0227x over previous
//
#include <hip/hip_runtime.h>
#include <hip/hip_bf16.h>
#include <math.h>

// Problem dims (fixed)
#define B 4
#define S 1024
#define E 512
#define H 64
#define DK 8
#define FFN 2048
#define BS (B*S)          // 4096 tokens

// kv pre-scale: CSCALE^2 = (1/sqrt(8)) * log2(e) so exp(score/sqrt(8)) = 2^(scaled score)
#define CSCALE 0.7141879f

#if __has_builtin(__builtin_amdgcn_exp2f)
#define EXP2F(x) __builtin_amdgcn_exp2f(x)
#else
#define EXP2F(x) exp2f(x)
#endif

typedef __attribute__((ext_vector_type(8))) short short8;   // 8 bf16 (4 VGPRs)
typedef __attribute__((ext_vector_type(4))) float float4a;  // MFMA C/D frag

union U8 { short8 v; unsigned u[4]; };
union F4 { float4a v; float f[4]; };

__device__ __forceinline__ unsigned short f2bf(float f) {
    unsigned u = __builtin_bit_cast(unsigned, f);
    u = (u + 0x7fffu + ((u >> 16) & 1u)) >> 16;
    return (unsigned short)u;
}
__device__ __forceinline__ float bf2f(unsigned short h) {
    return __builtin_bit_cast(float, (unsigned)h << 16);
}
// one-op pack: (trunc_bf16(a) << 16) | trunc_bf16(b)
__device__ __forceinline__ unsigned packbf(float a, float b) {
    return __builtin_amdgcn_perm(__builtin_bit_cast(unsigned, a),
                                 __builtin_bit_cast(unsigned, b), 0x07060302u);
}
__device__ __forceinline__ unsigned packbf_rn(float a, float b) {
    return ((unsigned)f2bf(a) << 16) | f2bf(b);
}
// key permutation within 32-blocks (attention PV): frag pos g*8+4h+r <-> key 16h+4g+r
// Preserves low 2 bits -> even row pairs map to adjacent slots.
__device__ __forceinline__ int pidx(int k) {
    return (k & ~31) | (((k >> 2) & 3) << 3) | (((k >> 4) & 1) << 2) | (k & 3);
}

// ---------------------------------------------------------------------------
// K1: [blocks 0..1023] MFMA attention — QUARTER-head blocks (512 thr, 8 waves,
//     wave = 2 q-tiles of 16). 1024 blocks -> 4 blocks/CU co-resident
//     (LDS 35.3 KB), 32 waves/CU for trans-pipe overlap.
//     [blocks 1024..1359] weight conversion to frag-major bf16.
// ---------------------------------------------------------------------------
__global__ __launch_bounds__(512) void attn_conv_kernel(const float* __restrict__ x,
                                                        const float* __restrict__ phi,
                                                        const float* __restrict__ Wc,
                                                        const float* __restrict__ W2,
                                                        const float* __restrict__ W1,
                                                        const float* __restrict__ b1,
                                                        unsigned short* __restrict__ Afrag,
                                                        unsigned short* __restrict__ W2f,
                                                        unsigned short* __restrict__ Wcf,
                                                        unsigned short* __restrict__ W1f) {
    __shared__ unsigned short kv[(S + 16) * DK];   // 16.25 KB, rows S..S+15 zero
    __shared__ unsigned short vtp[9][S + 8];       // 18.6 KB [dim0..7 + ones][perm key]
    int bid = blockIdx.x;
    int tid = threadIdx.x;

    if (bid >= 1024) {                              // ---- convert part ----
        int idx = (bid - 1024) * 512 + tid;
        if (idx < 131072) {                         // W2f (pi-permuted k)
            int lane = idx & 63, c = idx >> 6;
            int ntile = c >> 6, kb32 = c & 63;
            int g = lane >> 4, col = lane & 15;
            int n = ntile * 16 + col, kb = kb32 * 32;
            short8 o;
            #pragma unroll
            for (int j = 0; j < 8; j++) {
                int k = kb + 16 * (j >> 2) + 4 * g + (j & 3);
                o[j] = (short)f2bf(W2[(size_t)k * 512 + n]);
            }
            *(short8*)&W2f[(size_t)idx * 8] = o;
        } else if (idx < 163840) {                  // Wcf (direct frag order)
            int i2 = idx - 131072;
            int lane = i2 & 63, c = i2 >> 6;
            int ntile = c >> 4, kb32 = c & 15;
            int g = lane >> 4, col = lane & 15;
            int n = ntile * 16 + col, kb = kb32 * 32;
            short8 o;
            #pragma unroll
            for (int j = 0; j < 8; j++)
                o[j] = (short)f2bf(Wc[(size_t)(kb + g * 8 + j) * 512 + n]);
            *(short8*)&Wcf[(size_t)i2 * 8] = o;
        } else {                                    // W1f (b1 folded at slot 8)
            int i3 = idx - 163840;
            int lane = i3 & 63, c = i3 >> 6;
            int g = lane >> 4, col = lane & 15;
            int f = (c >> 1) * 32 + (c & 1) * 16 + col;
            short8 o = {0,0,0,0,0,0,0,0};
            if (g == 0) {
                #pragma unroll
                for (int j = 0; j < 8; j++) o[j] = (short)f2bf(W1[j * FFN + f]);
            } else if (g == 1) {
                o[0] = (short)f2bf(b1[f]);
            }
            *(short8*)&W1f[(size_t)i3 * 8] = o;
        }
        return;
    }

    // ---- attention part ----
    int head = bid >> 2, qquad = bid & 3;
    int b = head >> 6, hh = head & 63;

    float ph[DK];
    #pragma unroll
    for (int d = 0; d < DK; d++) ph[d] = phi[d];

    const short8 z8 = {0,0,0,0,0,0,0,0};
    {                                       // 2 consecutive rows per thread
        int r2 = tid * 2;
        unsigned short vb[8][2];
        #pragma unroll
        for (int j = 0; j < 2; j++) {
            const float* xp = x + ((size_t)(b * S + r2 + j)) * E + hh * DK;
            float4 u = *(const float4*)xp;
            float4 v = *(const float4*)(xp + 4);
            float c[8] = {__cosf(u.x+ph[0]), __cosf(u.y+ph[1]), __cosf(u.z+ph[2]), __cosf(u.w+ph[3]),
                          __cosf(v.x+ph[4]), __cosf(v.y+ph[5]), __cosf(v.z+ph[6]), __cosf(v.w+ph[7])};
            U8 kr;
            kr.u[0] = packbf_rn(c[1] * CSCALE, c[0] * CSCALE);
            kr.u[1] = packbf_rn(c[3] * CSCALE, c[2] * CSCALE);
            kr.u[2] = packbf_rn(c[5] * CSCALE, c[4] * CSCALE);
            kr.u[3] = packbf_rn(c[7] * CSCALE, c[6] * CSCALE);
            *(short8*)&kv[(r2 + j) * DK] = kr.v;    // ds_write_b128
            #pragma unroll
            for (int d = 0; d < 8; d++) vb[d][j] = f2bf(c[d]);
        }
        int pr = pidx(r2);                  // even row pair -> adjacent slots
        #pragma unroll
        for (int d = 0; d < 8; d++)
            *(unsigned*)&vtp[d][pr] = (unsigned)vb[d][0] | ((unsigned)vb[d][1] << 16);
        *(unsigned*)&vtp[8][pr] = 0x3F803F80u;      // ones (denominator row)
    }
    if (tid < 16) *(short8*)&kv[(S + tid) * DK] = z8;   // zero rows
    __syncthreads();

    int w = tid >> 6, lane = tid & 63, col = lane & 15, g = lane >> 4;
    bool g0 = (g == 0);
    int q0 = qquad * 256 + w * 32;
    const float4a zc = {0.f,0.f,0.f,0.f};

    short8 aq[2];                            // Q B-frags, 2 q-tiles of 16
    #pragma unroll
    for (int t = 0; t < 2; t++)
        aq[t] = g0 ? *(const short8*)&kv[(q0 + t*16 + col) * DK] : z8;

    float4a acc[2];
    acc[0] = zc; acc[1] = zc;

    int vrow = col < 8 ? col : 8;            // clamp: dims 9..15 get denom dups
    const unsigned short* vbase = &vtp[vrow][0];

    int off0 = g0 ? col * DK : S * DK;       // zero-row pointer trick
    int off1 = g0 ? (16 + col) * DK : S * DK;
    int stepo = g0 ? 32 * DK : 0;

    for (int kb = 0; kb < S; kb += 32) {
        short8 bk0 = *(const short8*)&kv[off0];
        short8 bk1 = *(const short8*)&kv[off1];
        off0 += stepo; off1 += stepo;
        short8 vf = *(const short8*)(vbase + kb + g * 8);
        #pragma unroll
        for (int t = 0; t < 2; t++) {
            float4a s0 = __builtin_amdgcn_mfma_f32_16x16x32_bf16(bk0, aq[t], zc, 0,0,0);
            float4a s1 = __builtin_amdgcn_mfma_f32_16x16x32_bf16(bk1, aq[t], zc, 0,0,0);
            F4 S0, S1; S0.v = s0; S1.v = s1;
            float e00 = EXP2F(S0.f[0]);
            float e01 = EXP2F(S0.f[1]);
            float e02 = EXP2F(S0.f[2]);
            float e03 = EXP2F(S0.f[3]);
            float e10 = EXP2F(S1.f[0]);
            float e11 = EXP2F(S1.f[1]);
            float e12 = EXP2F(S1.f[2]);
            float e13 = EXP2F(S1.f[3]);
            U8 pf;                           // lane-local P^T B-frag (pi-ordered keys)
            pf.u[0] = packbf(e01, e00);
            pf.u[1] = packbf(e03, e02);
            pf.u[2] = packbf(e11, e10);
            pf.u[3] = packbf(e13, e12);
            acc[t] = __builtin_amdgcn_mfma_f32_16x16x32_bf16(vf, pf.v, acc[t], 0,0,0);
        }
    }
    // acc[t]: O'[dim=4g+r][q=col]; denom = dim 8 = lane 32+col, reg 0
    int lp8 = ((hh & 3) * 16 + col) * 8;     // lane' * 8 (u16 units)
    #pragma unroll
    for (int t = 0; t < 2; t++) {
        F4 a; a.v = acc[t];
        float denom = __shfl(a.f[0], 32 + col);
        float inv = __builtin_amdgcn_rcpf(denom);
        if (g < 2) {
            int chunk = (hh >> 2) * 256 + (b * 64 + qquad * 16 + w * 2 + t);
            uint2 o;
            o.x = packbf_rn(a.f[1] * inv, a.f[0] * inv);
            o.y = packbf_rn(a.f[3] * inv, a.f[2] * inv);
            *(uint2*)&Afrag[(size_t)chunk * 512 + lp8 + g * 4] = o;
        }
    }
}

// ---------------------------------------------------------------------------
// K2: combine-heads GEMM + fused LN1 + qout (validated R8/R10/R11).
// Block = 16 tokens x full 512 n (8 waves x 4 ntiles).
// ---------------------------------------------------------------------------
__global__ __launch_bounds__(512) void combine_ln1(const unsigned short* __restrict__ Afrag,
                                                   const unsigned short* __restrict__ Wcf,
                                                   const float* __restrict__ bc,
                                                   const float* __restrict__ x,
                                                   const float* __restrict__ g1,
                                                   const float* __restrict__ be1,
                                                   float* __restrict__ x1out,
                                                   unsigned short* __restrict__ qoutbf,
                                                   const float* __restrict__ theta) {
    __shared__ unsigned short As[16 * 64 * 8];      // 16 KB
    __shared__ float xout[16][516];                 // 33 KB
    int tt = blockIdx.x;
    int tid = threadIdx.x;

    for (int i = tid; i < 1024; i += 512)
        *(short8*)&As[i * 8] =
            *(const short8*)&Afrag[((size_t)((i >> 6) * 256 + tt) * 64 + (i & 63)) * 8];
    __syncthreads();

    int w = tid >> 6, lane = tid & 63, col = lane & 15, g = lane >> 4;
    const float4a zc = {0.f,0.f,0.f,0.f};
    float4a acc[4];
    #pragma unroll
    for (int nt = 0; nt < 4; nt++) acc[nt] = zc;

    for (int kb32 = 0; kb32 < 16; kb32++) {
        short8 af = *(const short8*)&As[(kb32 * 64 + lane) * 8];
        #pragma unroll
        for (int nt = 0; nt < 4; nt++) {
            short8 bf = *(const short8*)&Wcf[((size_t)((w * 4 + nt) * 16 + kb32) * 64 + lane) * 8];
            acc[nt] = __builtin_amdgcn_mfma_f32_16x16x32_bf16(af, bf, acc[nt], 0, 0, 0);
        }
    }
    #pragma unroll
    for (int nt = 0; nt < 4; nt++) {
        int n = w * 64 + nt * 16 + col;
        float bb = bc[n];
        #pragma unroll
        for (int r = 0; r < 4; r++)
            xout[g * 4 + r][n] = acc[nt][r] + bb;
    }
    __syncthreads();

    int hl = lane >> 5, l = lane & 31;
    int token = w * 2 + hl;
    int e0 = l * 16;
    size_t grow = ((size_t)tt * 16 + token) * 512;
    float v[16];
    float s = 0.f, sq = 0.f;
    #pragma unroll
    for (int u = 0; u < 4; u++) {
        float4 xv = *(const float4*)&x[grow + e0 + u * 4];
        float4 pv = *(const float4*)&xout[token][e0 + u * 4];
        float a0 = xv.x + pv.x, a1 = xv.y + pv.y, a2 = xv.z + pv.z, a3 = xv.w + pv.w;
        v[u*4] = a0; v[u*4+1] = a1; v[u*4+2] = a2; v[u*4+3] = a3;
        s += a0 + a1 + a2 + a3;
        sq += a0*a0 + a1*a1 + a2*a2 + a3*a3;
    }
    #pragma unroll
    for (int off = 1; off <= 16; off <<= 1) {
        s  += __shfl_xor(s, off);
        sq += __shfl_xor(sq, off);
    }
    float mu = s * (1.f / 512.f);
    float var = sq * (1.f / 512.f) - mu * mu;
    float rstd = rsqrtf(var + 1e-5f);
    float y[16];
    #pragma unroll
    for (int u = 0; u < 4; u++) {
        float4 gv = *(const float4*)&g1[e0 + u * 4];
        float4 bv = *(const float4*)&be1[e0 + u * 4];
        y[u*4]   = (v[u*4]   - mu) * rstd * gv.x + bv.x;
        y[u*4+1] = (v[u*4+1] - mu) * rstd * gv.y + bv.y;
        y[u*4+2] = (v[u*4+2] - mu) * rstd * gv.z + bv.z;
        y[u*4+3] = (v[u*4+3] - mu) * rstd * gv.w + bv.w;
        float4 o = make_float4(y[u*4], y[u*4+1], y[u*4+2], y[u*4+3]);
        *(float4*)&x1out[grow + e0 + u * 4] = o;
    }
    if (l == 0) {
        U8 q;
        q.u[0] = packbf_rn(__cosf(y[1]) * __cosf(theta[1]), __cosf(y[0]) * __cosf(theta[0]));
        q.u[1] = packbf_rn(__cosf(y[3]) * __cosf(theta[3]), __cosf(y[2]) * __cosf(theta[2]));
        q.u[2] = packbf_rn(__cosf(y[5]) * __cosf(theta[5]), __cosf(y[4]) * __cosf(theta[4]));
        q.u[3] = packbf_rn(__cosf(y[7]) * __cosf(theta[7]), __cosf(y[6]) * __cosf(theta[6]));
        *(short8*)&qoutbf[((size_t)tt * 16 + token) * 8] = q.v;
    }
}

// ---------------------------------------------------------------------------
// K3: FFN (R8 version — n-tiled, W1+b1 staged in LDS). Validated.
// Wave = 32 tokens x 32 n; block = 256 tok x 32 n; grid (16,16).
// ---------------------------------------------------------------------------
__global__ __launch_bounds__(512) void ffn_mfma(const unsigned short* __restrict__ qbf,
                                                const unsigned short* __restrict__ W1fg,
                                                const unsigned short* __restrict__ W2f,
                                                const float* __restrict__ b2,
                                                unsigned short* __restrict__ Cbf) {
    __shared__ unsigned short w1x[FFN * 16];   // 64 KB: [f][slot], slot8 = b1[f]
    int tid = threadIdx.x;
    #pragma unroll
    for (int i = 0; i < 8; i++) {
        int d = tid + i * 512;                 // d = f*2 + gg
        int f = d >> 1, gg = d & 1;
        int kb32 = f >> 5, half = (f >> 4) & 1, fc = f & 15;
        int src = ((kb32 * 2 + half) * 64 + gg * 16 + fc);
        *(short8*)&w1x[f * 16 + gg * 8] = *(const short8*)&W1fg[(size_t)src * 8];
    }
    __syncthreads();

    int w = tid >> 6, lane = tid & 63, col = lane & 15, g = lane >> 4;
    int mw = blockIdx.x * 256 + w * 32;
    int ntile0 = blockIdx.y * 2;
    const short8 z8 = {0,0,0,0,0,0,0,0};
    const short8 one8 = {(short)0x3F80,0,0,0,0,0,0,0};
    const float4a zc = {0.f,0.f,0.f,0.f};

    short8 qf[2];                              // B[k=qslot][n=tok]; slot8 = 1.0
    #pragma unroll
    for (int t = 0; t < 2; t++)
        qf[t] = (g == 0) ? *(const short8*)&qbf[(size_t)(mw + t * 16 + col) * 8]
                         : (g == 1 ? one8 : z8);

    float4a acc[2][2];
    acc[0][0] = zc; acc[0][1] = zc; acc[1][0] = zc; acc[1][1] = zc;

    const unsigned short* w2p0 = W2f + (size_t)(ntile0 * 64) * 512 + lane * 8;
    const unsigned short* w2p1 = W2f + (size_t)((ntile0 + 1) * 64) * 512 + lane * 8;

    for (int kb32 = 0; kb32 < 64; kb32++) {
        int kb = kb32 * 32;
        short8 w1f0 = (g < 2) ? *(const short8*)&w1x[(kb + col) * 16 + g * 8] : z8;
        short8 w1f1 = (g < 2) ? *(const short8*)&w1x[(kb + 16 + col) * 16 + g * 8] : z8;
        short8 af0 = *(const short8*)(w2p0 + (size_t)kb32 * 512);
        short8 af1 = *(const short8*)(w2p1 + (size_t)kb32 * 512);
        #pragma unroll
        for (int t = 0; t < 2; t++) {
            float4a h0 = __builtin_amdgcn_mfma_f32_16x16x32_bf16(w1f0, qf[t], zc, 0,0,0);
            float4a h1 = __builtin_amdgcn_mfma_f32_16x16x32_bf16(w1f1, qf[t], zc, 0,0,0);
            F4 H0, H1; H0.v = h0; H1.v = h1;
            float e00 = fmaxf(H0.f[0], 0.f);
            float e01 = fmaxf(H0.f[1], 0.f);
            float e02 = fmaxf(H0.f[2], 0.f);
            float e03 = fmaxf(H0.f[3], 0.f);
            float e10 = fmaxf(H1.f[0], 0.f);
            float e11 = fmaxf(H1.f[1], 0.f);
            float e12 = fmaxf(H1.f[2], 0.f);
            float e13 = fmaxf(H1.f[3], 0.f);
            U8 pf;                             // H^T B-frag, pi-ordered f
            pf.u[0] = packbf(e01, e00);
            pf.u[1] = packbf(e03, e02);
            pf.u[2] = packbf(e11, e10);
            pf.u[3] = packbf(e13, e12);
            acc[t][0] = __builtin_amdgcn_mfma_f32_16x16x32_bf16(af0, pf.v, acc[t][0], 0,0,0);
            acc[t][1] = __builtin_amdgcn_mfma_f32_16x16x32_bf16(af1, pf.v, acc[t][1], 0,0,0);
        }
    }
    int n0 = ntile0 * 16;
    #pragma unroll
    for (int nt = 0; nt < 2; nt++) {
        float4 bb = *(const float4*)&b2[n0 + nt * 16 + 4 * g];
        #pragma unroll
        for (int t = 0; t < 2; t++) {
            F4 a; a.v = acc[t][nt];
            uint2 o;
            o.x = packbf_rn(a.f[1] + bb.y, a.f[0] + bb.x);
            o.y = packbf_rn(a.f[3] + bb.w, a.f[2] + bb.z);
            *(uint2*)&Cbf[(size_t)(mw + t * 16 + col) * 512 + n0 + nt * 16 + 4 * g] = o;
        }
    }
}

// ---------------------------------------------------------------------------
// K4: final LayerNorm (x1 fp32 + ffn_out bf16), in-place on d_out.
// ---------------------------------------------------------------------------
__global__ __launch_bounds__(256) void ln_kernel(const float* a,
                                                 const unsigned short* __restrict__ r,
                                                 const float* __restrict__ g,
                                                 const float* __restrict__ be,
                                                 float* out) {
    int t = blockIdx.x, tid = threadIdx.x;
    size_t base = (size_t)t * E;
    int e0 = tid * 2;
    float2 av = *(const float2*)&a[base + e0];
    unsigned rv = *(const unsigned*)&r[base + e0];
    float v0 = av.x + bf2f((unsigned short)(rv & 0xffff));
    float v1 = av.y + bf2f((unsigned short)(rv >> 16));
    float s  = v0 + v1;
    float sq = v0 * v0 + v1 * v1;
    #pragma unroll
    for (int off = 32; off > 0; off >>= 1) {
        s  += __shfl_down(s, off);
        sq += __shfl_down(sq, off);
    }
    __shared__ float ls[4], lq[4];
    int wave = tid >> 6, lane = tid & 63;
    if (lane == 0) { ls[wave] = s; lq[wave] = sq; }
    __syncthreads();
    if (tid == 0) {
        float SS = ls[0] + ls[1] + ls[2] + ls[3];
        float QQ = lq[0] + lq[1] + lq[2] + lq[3];
        float mu = SS * (1.f / E);
        float var = QQ * (1.f / E) - mu * mu;
        ls[0] = mu;
        lq[0] = rsqrtf(var + 1e-5f);
    }
    __syncthreads();
    float mu = ls[0], rstd = lq[0];
    float2 gv = *(const float2*)&g[e0];
    float2 bv = *(const float2*)&be[e0];
    float y0 = (v0 - mu) * rstd * gv.x + bv.x;
    float y1 = (v1 - mu) * rstd * gv.y + bv.y;
    *(float2*)&out[base + e0] = make_float2(y0, y1);
}

// ---------------------------------------------------------------------------
// launch — 4 kernels. ws: Afrag/ffn_out 4MB | W2f 2MB | Wcf 0.5MB | W1f 128KB
// | qoutbf 64KB = 6.7 MB (under proven 8.13 MB). d_out: x1 fp32, LN2 in-place.
// ---------------------------------------------------------------------------
extern "C" void kernel_launch(void* const* d_in, const int* in_sizes, int n_in,
                              void* d_out, int out_size, void* d_ws, size_t ws_size,
                              hipStream_t stream) {
    const float* x     = (const float*)d_in[0];
    const float* phi   = (const float*)d_in[1];
    const float* Wc    = (const float*)d_in[2];
    const float* bc    = (const float*)d_in[3];
    const float* theta = (const float*)d_in[4];
    const float* W1    = (const float*)d_in[5];
    const float* b1    = (const float*)d_in[6];
    const float* W2    = (const float*)d_in[7];
    const float* b2    = (const float*)d_in[8];
    const float* g1    = (const float*)d_in[9];
    const float* be1   = (const float*)d_in[10];
    const float* g2    = (const float*)d_in[11];
    const float* be2   = (const float*)d_in[12];
    float* out = (float*)d_out;

    float* ws = (float*)d_ws;
    unsigned short* Afrag  = (unsigned short*)ws;                       // 4 MB (also ffn_out)
    unsigned short* W2f    = (unsigned short*)(ws + 1048576);           // 2 MB
    unsigned short* Wcf    = (unsigned short*)(ws + 1572864);           // 512 KB
    unsigned short* W1f    = (unsigned short*)(ws + 1703936);           // 128 KB
    unsigned short* qoutbf = (unsigned short*)(ws + 1736704);           // 64 KB

    attn_conv_kernel<<<1360, 512, 0, stream>>>(x, phi, Wc, W2, W1, b1,
                                               Afrag, W2f, Wcf, W1f);
    combine_ln1<<<256, 512, 0, stream>>>(Afrag, Wcf, bc, x, g1, be1,
                                         out, qoutbf, theta);
    ffn_mfma<<<dim3(16, 16), 512, 0, stream>>>(qoutbf, W1f, W2f, b2, Afrag);
    ln_kernel<<<BS, 256, 0, stream>>>(out, Afrag, g2, be2, out);
}